// Round 1
// baseline (585.289 us; speedup 1.0000x reference)
//
#include <hip/hip_runtime.h>
#include <stdint.h>

typedef unsigned short u16;
typedef __attribute__((ext_vector_type(8))) short short8v;
typedef __attribute__((ext_vector_type(4))) float float4v;

static __device__ __forceinline__ u16 f2bf(float f) {
    union { float f; uint32_t u; } v; v.f = f;
    uint32_t u = v.u;
    uint32_t r = (u + 0x7fffu + ((u >> 16) & 1u)) >> 16;
    return (u16)r;
}

// ---------------------------------------------------------------------------
// Kernel: convert w2 [1024,4096] fp32 -> bf16
// grid 4096 x 256 threads, 4 elems/thread
// ---------------------------------------------------------------------------
__global__ __launch_bounds__(256) void w2cvt_kernel(const float* __restrict__ w2,
                                                    u16* __restrict__ W) {
    size_t i = ((size_t)blockIdx.x * 256 + threadIdx.x) * 4;
    float4 v = *(const float4*)&w2[i];
    ushort4 o;
    o.x = f2bf(v.x); o.y = f2bf(v.y); o.z = f2bf(v.z); o.w = f2bf(v.w);
    *(ushort4*)&W[i] = o;
}

// ---------------------------------------------------------------------------
// Kernel: H[r, f] = relu( sum_i q[r,i]*w1[f,i] + b1[f] ) as bf16
// q[r,i] = cos(x[m0+r, i]) * cos(theta[i]),  ROWS=16 rows per block
// ---------------------------------------------------------------------------
__global__ __launch_bounds__(256) void h_kernel(const float* __restrict__ x,
                                                const float* __restrict__ theta,
                                                const float* __restrict__ w1,
                                                const float* __restrict__ b1,
                                                u16* __restrict__ H, int m0) {
    constexpr int ROWS = 16;
    __shared__ float qs[ROWS][8];
    const int tid = threadIdx.x;
    const int r0 = blockIdx.x * ROWS;
    if (tid < ROWS * 8) {
        int r = tid >> 3, i = tid & 7;
        qs[r][i] = cosf(x[(size_t)(m0 + r0 + r) * 1024 + i]) * cosf(theta[i]);
    }
    __syncthreads();
    // 4096 f-columns = 1024 quads; 256 threads -> 4 quads each
    for (int qi = 0; qi < 4; ++qi) {
        const int f4 = (qi * 256 + tid) * 4;
        float4 wa[4], wb[4];
        float bb[4];
#pragma unroll
        for (int c = 0; c < 4; ++c) {
            wa[c] = *(const float4*)&w1[(size_t)(f4 + c) * 8];
            wb[c] = *(const float4*)&w1[(size_t)(f4 + c) * 8 + 4];
            bb[c] = b1[f4 + c];
        }
        for (int r = 0; r < ROWS; ++r) {
            float qv[8];
#pragma unroll
            for (int i = 0; i < 8; ++i) qv[i] = qs[r][i];
            ushort4 hv;
#pragma unroll
            for (int c = 0; c < 4; ++c) {
                float a = bb[c];
                a += qv[0] * wa[c].x + qv[1] * wa[c].y + qv[2] * wa[c].z + qv[3] * wa[c].w;
                a += qv[4] * wb[c].x + qv[5] * wb[c].y + qv[6] * wb[c].z + qv[7] * wb[c].w;
                a = fmaxf(a, 0.f);
                ((u16*)&hv)[c] = f2bf(a);
            }
            *(ushort4*)&H[(size_t)(r0 + r) * 4096 + f4] = hv;
        }
    }
}

// ---------------------------------------------------------------------------
// Kernel: C[m,n] = sum_k A[m,k]*B[n,k] + b2[n]   (both row-major, K-contig)
// A = H chunk bf16 [rows, 4096], B = w2 bf16 [1024, 4096], C fp32
// m97 structure: 128x128 tile, BK=64, 4 waves, global_load_lds w/ pre-swizzled
// source so ds_read_b128 with byte ^= (row&7)<<4 is bank-conflict-free.
// ---------------------------------------------------------------------------
__global__ __launch_bounds__(256) void gemm_kernel(const u16* __restrict__ A,
                                                   const u16* __restrict__ B,
                                                   const float* __restrict__ b2,
                                                   float* __restrict__ C) {
    constexpr int K = 4096, N = 1024;
    constexpr int BM = 128, BK = 64;
    constexpr int NKS = K / BK;  // 64
    __shared__ __align__(16) u16 lds[2 * 8192];  // A: bytes [0,16K), B: [16K,32K)

    const int tid = threadIdx.x;
    const int wv = tid >> 6, lane = tid & 63;
    const int bn = blockIdx.x & 7, bm = blockIdx.x >> 3;

    auto stage = [&](int ks) {
#pragma unroll
        for (int i = 0; i < 4; ++i) {
            const int sp = wv * 4 + i;          // span of 1024 B (64 lanes x 16 B)
            const int li = sp * 64 + lane;      // 16-byte unit index 0..1023
            const int row = li >> 3;            // tile row 0..127
            const int j = li & 7;               // 16B slot within the 128B row
            const int koff = 8 * (j ^ (row & 7));  // inverse-swizzled k offset
            const u16* srcA = A + (size_t)(bm * BM + row) * K + ks * BK + koff;
            __builtin_amdgcn_global_load_lds(
                (const __attribute__((address_space(1))) void*)srcA,
                (__attribute__((address_space(3))) void*)&lds[sp * 512], 16, 0, 0);
            const u16* srcB = B + (size_t)(bn * BM + row) * K + ks * BK + koff;
            __builtin_amdgcn_global_load_lds(
                (const __attribute__((address_space(1))) void*)srcB,
                (__attribute__((address_space(3))) void*)&lds[8192 + sp * 512], 16, 0, 0);
        }
    };

    float4v acc[4][4];
#pragma unroll
    for (int mi = 0; mi < 4; ++mi)
#pragma unroll
        for (int ni = 0; ni < 4; ++ni)
            acc[mi][ni] = (float4v){0.f, 0.f, 0.f, 0.f};

    const int wm = (wv & 1) * 64, wn = (wv >> 1) * 64;
    const int lr = lane & 15, kg = lane >> 4;

    stage(0);
    for (int ks = 0; ks < NKS; ++ks) {
        __syncthreads();  // compiler emits vmcnt(0) drain: staged tile ready
#pragma unroll
        for (int kk = 0; kk < 2; ++kk) {
            short8v av[4], bv[4];
#pragma unroll
            for (int mi = 0; mi < 4; ++mi) {
                const int row = wm + mi * 16 + lr;
                const int byteoff = row * 128 + ((kk * 64 + kg * 16) ^ ((row & 7) << 4));
                av[mi] = *(const short8v*)((const char*)lds + byteoff);
            }
#pragma unroll
            for (int ni = 0; ni < 4; ++ni) {
                const int row = wn + ni * 16 + lr;
                const int byteoff = 16384 + row * 128 + ((kk * 64 + kg * 16) ^ ((row & 7) << 4));
                bv[ni] = *(const short8v*)((const char*)lds + byteoff);
            }
#pragma unroll
            for (int mi = 0; mi < 4; ++mi)
#pragma unroll
                for (int ni = 0; ni < 4; ++ni)
                    acc[mi][ni] = __builtin_amdgcn_mfma_f32_16x16x32_bf16(
                        av[mi], bv[ni], acc[mi][ni], 0, 0, 0);
        }
        __syncthreads();  // all LDS reads done before restaging
        if (ks + 1 < NKS) stage(ks + 1);
    }

    // epilogue: C/D layout col=lane&15, row=(lane>>4)*4+j  [m89-verified]
    float b2v[4];
#pragma unroll
    for (int ni = 0; ni < 4; ++ni) b2v[ni] = b2[bn * BM + wn + ni * 16 + lr];
#pragma unroll
    for (int mi = 0; mi < 4; ++mi)
#pragma unroll
        for (int ni = 0; ni < 4; ++ni) {
            const int col = bn * BM + wn + ni * 16 + lr;
#pragma unroll
            for (int j = 0; j < 4; ++j) {
                const int row = bm * BM + wm + mi * 16 + kg * 4 + j;
                C[(size_t)row * N + col] = acc[mi][ni][j] + b2v[ni];
            }
        }
}

// ---------------------------------------------------------------------------
// Fallback (only if ws too small): fp32, one row per block. Slow but correct.
// ---------------------------------------------------------------------------
__global__ __launch_bounds__(256) void naive_kernel(const float* __restrict__ x,
                                                    const float* __restrict__ theta,
                                                    const float* __restrict__ w1,
                                                    const float* __restrict__ b1,
                                                    const float* __restrict__ w2,
                                                    const float* __restrict__ b2,
                                                    float* __restrict__ out) {
    const int m = blockIdx.x;
    __shared__ float h[4096];
    __shared__ float q[8];
    if (threadIdx.x < 8)
        q[threadIdx.x] = cosf(x[(size_t)m * 1024 + threadIdx.x]) * cosf(theta[threadIdx.x]);
    __syncthreads();
    for (int f = threadIdx.x; f < 4096; f += 256) {
        float a = b1[f];
#pragma unroll
        for (int i = 0; i < 8; ++i) a += q[i] * w1[(size_t)f * 8 + i];
        h[f] = fmaxf(a, 0.f);
    }
    __syncthreads();
    for (int e = threadIdx.x; e < 1024; e += 256) {
        float a = b2[e];
        const float* wr = w2 + (size_t)e * 4096;
        for (int f = 0; f < 4096; ++f) a += h[f] * wr[f];
        out[(size_t)m * 1024 + e] = a;
    }
}

extern "C" void kernel_launch(void* const* d_in, const int* in_sizes, int n_in,
                              void* d_out, int out_size, void* d_ws, size_t ws_size,
                              hipStream_t stream) {
    const float* x     = (const float*)d_in[0];
    const float* theta = (const float*)d_in[1];
    const float* w1    = (const float*)d_in[2];
    const float* b1    = (const float*)d_in[3];
    const float* w2    = (const float*)d_in[4];
    const float* b2    = (const float*)d_in[5];
    float* out = (float*)d_out;

    const int M = 32768, K = 4096, N = 1024;
    const size_t w2b_bytes = (size_t)N * K * 2;  // 8 MiB

    size_t avail = ws_size > w2b_bytes ? ws_size - w2b_bytes : 0;
    long long mc_ll = (long long)(avail / ((size_t)K * 2));
    int Mc = (int)((mc_ll > 32768) ? 32768 : mc_ll);
    Mc = (Mc / 128) * 128;
    if (Mc > 8192) Mc = 8192;  // keep H chunk (64 MB) L3-resident

    if (Mc < 128) {
        // emergency fallback: no usable workspace
        naive_kernel<<<dim3(M), dim3(256), 0, stream>>>(x, theta, w1, b1, w2, b2, out);
        return;
    }

    u16* w2b = (u16*)d_ws;
    u16* Hb  = (u16*)((char*)d_ws + w2b_bytes);

    w2cvt_kernel<<<dim3((N * K) / 1024), dim3(256), 0, stream>>>(w2, w2b);

    for (int m0 = 0; m0 < M; m0 += Mc) {
        const int rows = (M - m0 < Mc) ? (M - m0) : Mc;
        h_kernel<<<dim3(rows / 16), dim3(256), 0, stream>>>(x, theta, w1, b1, Hb, m0);
        gemm_kernel<<<dim3((rows / 128) * 8), dim3(256), 0, stream>>>(
            Hb, w2b, b2, out + (size_t)m0 * N);
    }
}

// Round 4
// 559.427 us; speedup vs baseline: 1.0462x; 1.0462x over previous
//
#include <hip/hip_runtime.h>
#include <stdint.h>

typedef unsigned short u16;
typedef __attribute__((ext_vector_type(8))) short short8v;
typedef __attribute__((ext_vector_type(4))) float float4v;

static __device__ __forceinline__ u16 f2bf(float f) {
    union { float f; uint32_t u; } v; v.f = f;
    uint32_t u = v.u;
    uint32_t r = (u + 0x7fffu + ((u >> 16) & 1u)) >> 16;
    return (u16)r;
}

// ---------------------------------------------------------------------------
// w2 [1024,4096] fp32 -> bf16
// ---------------------------------------------------------------------------
__global__ __launch_bounds__(256) void w2cvt_kernel(const float* __restrict__ w2,
                                                    u16* __restrict__ W) {
    size_t i = ((size_t)blockIdx.x * 256 + threadIdx.x) * 4;
    float4 v = *(const float4*)&w2[i];
    ushort4 o;
    o.x = f2bf(v.x); o.y = f2bf(v.y); o.z = f2bf(v.z); o.w = f2bf(v.w);
    *(ushort4*)&W[i] = o;
}

// ---------------------------------------------------------------------------
// H[r,f] = relu(sum_i q[r,i]*w1[f,i] + b1[f]) in bf16.
// Block: 256 threads, 32 rows, half of F (thread owns 8 consecutive f,
// w1 slice held in 64 VGPRs across all 32 rows; one 16B store per row).
// ---------------------------------------------------------------------------
__global__ __launch_bounds__(256) void h_kernel(const float* __restrict__ x,
                                                const float* __restrict__ theta,
                                                const float* __restrict__ w1,
                                                const float* __restrict__ b1,
                                                u16* __restrict__ H, int m0) {
    __shared__ float qs[32][8];
    const int tid = threadIdx.x;
    const int rb = blockIdx.x >> 1;
    const int fb = blockIdx.x & 1;
    const int r0 = rb * 32;
    {
        int r = tid >> 3, i = tid & 7;
        qs[r][i] = cosf(x[(size_t)(m0 + r0 + r) * 1024 + i]) * cosf(theta[i]);
    }
    __syncthreads();
    const int f8 = (fb * 256 + tid) * 8;
    float4 w[16];
    float bb[8];
#pragma unroll
    for (int c = 0; c < 8; ++c) {
        w[2 * c]     = *(const float4*)&w1[(size_t)(f8 + c) * 8];
        w[2 * c + 1] = *(const float4*)&w1[(size_t)(f8 + c) * 8 + 4];
        bb[c] = b1[f8 + c];
    }
    for (int r = 0; r < 32; ++r) {
        float qv[8];
#pragma unroll
        for (int i = 0; i < 8; ++i) qv[i] = qs[r][i];
        short8v hv;
#pragma unroll
        for (int c = 0; c < 8; ++c) {
            float a = bb[c];
            a += qv[0] * w[2*c].x + qv[1] * w[2*c].y + qv[2] * w[2*c].z + qv[3] * w[2*c].w;
            a += qv[4] * w[2*c+1].x + qv[5] * w[2*c+1].y + qv[6] * w[2*c+1].z + qv[7] * w[2*c+1].w;
            a = fmaxf(a, 0.f);
            hv[c] = (short)f2bf(a);
        }
        *(short8v*)&H[(size_t)(r0 + r) * 4096 + f8] = hv;
    }
}

// ---------------------------------------------------------------------------
// GEMM: C[m,n] = sum_k A[m,k]*B[n,k] + b2[n], A [rows,4096] bf16 (rows%256==0),
// B = w2 bf16 [1024,4096], C fp32.
// BM=256, BN=128, BK=64. 8 waves (4M x 2N), per-wave 64x64 output (4x4 frags).
// Triple-buffered LDS ring (144 KiB): compute kt from buf[kt%3], stage kt+2
// into buf[(kt+2)%3] (= buffer retired at kt-1's end barrier -> race-free).
// 2 phases per K-tile; counted s_waitcnt vmcnt(6) once per K-tile (T4);
// setprio around MFMA cluster (T5); XOR-swizzled LDS via pre-swizzled global
// source (T2, round-1-verified: 0 bank conflicts); XCD-chunked swizzle (T1).
// ---------------------------------------------------------------------------
__global__ __launch_bounds__(512, 2) void gemm_kernel(const u16* __restrict__ A,
                                                      const u16* __restrict__ B,
                                                      const float* __restrict__ b2,
                                                      float* __restrict__ C, int nbm) {
    constexpr int K = 4096, N = 1024;
    constexpr int NKT = K / 64;
    __shared__ __align__(16) u16 lds[3 * 24576];  // 3 x (A 32KB + B 16KB)

    const int tid = threadIdx.x;
    const int wv = tid >> 6, lane = tid & 63;

    // XCD-chunked bijective swizzle (nwg = nbm*8, divisible by 8)
    const int qq = nbm;  // nwg/8
    const int bid = (int)blockIdx.x;
    const int lbid = (bid & 7) * qq + (bid >> 3);
    const int bm = lbid >> 3, bn = lbid & 7;

    const u16* Ab = A + (size_t)bm * 256 * K;
    const u16* Bb = B + (size_t)bn * 128 * K;

    // Per-thread staging descriptors (inverse-swizzled global source, linear LDS dst)
    const u16* srcA[4]; int dstA[4];
#pragma unroll
    for (int u = 0; u < 4; ++u) {
        const int idx = u * 512 + tid;       // 16B slot in A tile (0..2047)
        const int row = idx >> 3, j = idx & 7;
        srcA[u] = Ab + (size_t)row * K + 8 * (j ^ (row & 7));
        dstA[u] = idx * 8;                   // u16 offset
    }
    const u16* srcB[2]; int dstB[2];
#pragma unroll
    for (int u = 0; u < 2; ++u) {
        const int idx = u * 512 + tid;       // 16B slot in B tile (0..1023)
        const int row = idx >> 3, j = idx & 7;
        srcB[u] = Bb + (size_t)row * K + 8 * (j ^ (row & 7));
        dstB[u] = 16384 + idx * 8;
    }

#define STAGE_A(kt, bufbase, u)                                               \
    __builtin_amdgcn_global_load_lds(                                         \
        (const __attribute__((address_space(1))) void*)(srcA[u] + (kt) * 64), \
        (__attribute__((address_space(3))) void*)((bufbase) + dstA[u]), 16, 0, 0)
#define STAGE_B(kt, bufbase, u)                                               \
    __builtin_amdgcn_global_load_lds(                                         \
        (const __attribute__((address_space(1))) void*)(srcB[u] + (kt) * 64), \
        (__attribute__((address_space(3))) void*)((bufbase) + dstB[u]), 16, 0, 0)

    float4v acc[4][4];
#pragma unroll
    for (int mi = 0; mi < 4; ++mi)
#pragma unroll
        for (int ni = 0; ni < 4; ++ni)
            acc[mi][ni] = (float4v){0.f, 0.f, 0.f, 0.f};

    const int wm = (wv >> 1) * 64, wn = (wv & 1) * 64;
    const int lr = lane & 15, kg = lane >> 4;

    // prologue: stage tiles 0 and 1
    {
        u16* b0 = &lds[0];
        u16* b1b = &lds[24576];
        STAGE_A(0, b0, 0); STAGE_A(0, b0, 1); STAGE_A(0, b0, 2); STAGE_A(0, b0, 3);
        STAGE_B(0, b0, 0); STAGE_B(0, b0, 1);
        STAGE_A(1, b1b, 0); STAGE_A(1, b1b, 1); STAGE_A(1, b1b, 2); STAGE_A(1, b1b, 3);
        STAGE_B(1, b1b, 0); STAGE_B(1, b1b, 1);
    }
    asm volatile("s_waitcnt vmcnt(6)" ::: "memory");  // tile 0 landed
    __builtin_amdgcn_s_barrier();

    int bi = 0, si = 2;
    for (int kt = 0; kt < NKT; ++kt) {
        char* buf = (char*)&lds[bi * 24576];
        u16* sbuf = &lds[si * 24576];
        const bool doStage = (kt + 2 < NKT);

        // -------- phase 1 (kk = 0) --------
        if (doStage) { STAGE_A(kt + 2, sbuf, 0); STAGE_A(kt + 2, sbuf, 1); STAGE_A(kt + 2, sbuf, 2); }
        short8v av0[4], bv0[4];
#pragma unroll
        for (int mi = 0; mi < 4; ++mi) {
            const int row = wm + mi * 16 + lr;
            av0[mi] = *(const short8v*)(buf + row * 128 + ((kg * 16) ^ ((row & 7) << 4)));
        }
#pragma unroll
        for (int ni = 0; ni < 4; ++ni) {
            const int row = wn + ni * 16 + lr;
            bv0[ni] = *(const short8v*)(buf + 32768 + row * 128 + ((kg * 16) ^ ((row & 7) << 4)));
        }
        __builtin_amdgcn_s_barrier();
        __builtin_amdgcn_s_setprio(1);
#pragma unroll
        for (int mi = 0; mi < 4; ++mi)
#pragma unroll
            for (int ni = 0; ni < 4; ++ni)
                acc[mi][ni] = __builtin_amdgcn_mfma_f32_16x16x32_bf16(
                    av0[mi], bv0[ni], acc[mi][ni], 0, 0, 0);
        __builtin_amdgcn_s_setprio(0);
        __builtin_amdgcn_s_barrier();

        // -------- phase 2 (kk = 1) --------
        if (doStage) { STAGE_A(kt + 2, sbuf, 3); STAGE_B(kt + 2, sbuf, 0); STAGE_B(kt + 2, sbuf, 1); }
        short8v av1[4], bv1[4];
#pragma unroll
        for (int mi = 0; mi < 4; ++mi) {
            const int row = wm + mi * 16 + lr;
            av1[mi] = *(const short8v*)(buf + row * 128 + ((64 + kg * 16) ^ ((row & 7) << 4)));
        }
#pragma unroll
        for (int ni = 0; ni < 4; ++ni) {
            const int row = wn + ni * 16 + lr;
            bv1[ni] = *(const short8v*)(buf + 32768 + row * 128 + ((64 + kg * 16) ^ ((row & 7) << 4)));
        }
        if (doStage) asm volatile("s_waitcnt vmcnt(6)" ::: "memory");  // tile kt+1 landed
        else         asm volatile("s_waitcnt vmcnt(0)" ::: "memory");  // drain tail
        __builtin_amdgcn_s_barrier();
        __builtin_amdgcn_s_setprio(1);
#pragma unroll
        for (int mi = 0; mi < 4; ++mi)
#pragma unroll
            for (int ni = 0; ni < 4; ++ni)
                acc[mi][ni] = __builtin_amdgcn_mfma_f32_16x16x32_bf16(
                    av1[mi], bv1[ni], acc[mi][ni], 0, 0, 0);
        __builtin_amdgcn_s_setprio(0);
        __builtin_amdgcn_s_barrier();

        bi = (bi == 2) ? 0 : bi + 1;
        si = (si == 2) ? 0 : si + 1;
    }
#undef STAGE_A
#undef STAGE_B

    // epilogue: C/D layout col=lane&15, row=(lane>>4)*4+j
    float b2v[4];
#pragma unroll
    for (int ni = 0; ni < 4; ++ni) b2v[ni] = b2[bn * 128 + wn + ni * 16 + lr];
#pragma unroll
    for (int mi = 0; mi < 4; ++mi)
#pragma unroll
        for (int ni = 0; ni < 4; ++ni) {
            const int col = bn * 128 + wn + ni * 16 + lr;
#pragma unroll
            for (int j = 0; j < 4; ++j) {
                const int row = bm * 256 + wm + mi * 16 + kg * 4 + j;
                C[(size_t)row * N + col] = acc[mi][ni][j] + b2v[ni];
            }
        }
}

// ---------------------------------------------------------------------------
// Fallback (ws too small): fp32, one row per block.
// ---------------------------------------------------------------------------
__global__ __launch_bounds__(256) void naive_kernel(const float* __restrict__ x,
                                                    const float* __restrict__ theta,
                                                    const float* __restrict__ w1,
                                                    const float* __restrict__ b1,
                                                    const float* __restrict__ w2,
                                                    const float* __restrict__ b2,
                                                    float* __restrict__ out) {
    const int m = blockIdx.x;
    __shared__ float h[4096];
    __shared__ float q[8];
    if (threadIdx.x < 8)
        q[threadIdx.x] = cosf(x[(size_t)m * 1024 + threadIdx.x]) * cosf(theta[threadIdx.x]);
    __syncthreads();
    for (int f = threadIdx.x; f < 4096; f += 256) {
        float a = b1[f];
#pragma unroll
        for (int i = 0; i < 8; ++i) a += q[i] * w1[(size_t)f * 8 + i];
        h[f] = fmaxf(a, 0.f);
    }
    __syncthreads();
    for (int e = threadIdx.x; e < 1024; e += 256) {
        float a = b2[e];
        const float* wr = w2 + (size_t)e * 4096;
        for (int f = 0; f < 4096; ++f) a += h[f] * wr[f];
        out[(size_t)m * 1024 + e] = a;
    }
}

extern "C" void kernel_launch(void* const* d_in, const int* in_sizes, int n_in,
                              void* d_out, int out_size, void* d_ws, size_t ws_size,
                              hipStream_t stream) {
    const float* x     = (const float*)d_in[0];
    const float* theta = (const float*)d_in[1];
    const float* w1    = (const float*)d_in[2];
    const float* b1    = (const float*)d_in[3];
    const float* w2    = (const float*)d_in[4];
    const float* b2    = (const float*)d_in[5];
    float* out = (float*)d_out;

    const int M = 32768, K = 4096, N = 1024;
    const size_t w2b_bytes = (size_t)N * K * 2;  // 8 MiB

    size_t avail = ws_size > w2b_bytes ? ws_size - w2b_bytes : 0;
    long long mc_ll = (long long)(avail / ((size_t)K * 2));
    int Mc = (int)((mc_ll > 32768) ? 32768 : mc_ll);
    Mc = (Mc / 256) * 256;
    if (Mc > 8192) Mc = 8192;  // keep H chunk (64 MB) L3-resident

    if (Mc < 256) {
        naive_kernel<<<dim3(M), dim3(256), 0, stream>>>(x, theta, w1, b1, w2, b2, out);
        return;
    }

    u16* w2b = (u16*)d_ws;
    u16* Hb  = (u16*)((char*)d_ws + w2b_bytes);

    w2cvt_kernel<<<dim3((N * K) / 1024), dim3(256), 0, stream>>>(w2, w2b);

    for (int m0 = 0; m0 < M; m0 += Mc) {
        const int rows = (M - m0 < Mc) ? (M - m0) : Mc;
        h_kernel<<<dim3((rows / 32) * 2), dim3(256), 0, stream>>>(x, theta, w1, b1, Hb, m0);
        const int nbm = rows / 256;
        gemm_kernel<<<dim3(nbm * 8), dim3(512), 0, stream>>>(Hb, w2b, b2, out + (size_t)m0 * N, nbm);
    }
}